// Round 1
// 442.210 us; speedup vs baseline: 1.0171x; 1.0171x over previous
//
#include <hip/hip_runtime.h>

#define T_STEPS 256
#define BATCH   128
#define FEAT    1536            // DH * L = 512 * 3
#define NPAIRS  (T_STEPS * BATCH)

// ---------------------------------------------------------------------------
// DPP full-wave (64-lane) sum. Result valid in lane 63. All VALU-pipe.
// ---------------------------------------------------------------------------
template <int CTRL, int RMASK>
__device__ __forceinline__ float dpp_add_step(float v) {
    int m = __builtin_amdgcn_update_dpp(0, __float_as_int(v), CTRL, RMASK, 0xF, true);
    return v + __int_as_float(m);
}

__device__ __forceinline__ float wave_reduce63(float v) {
    v = dpp_add_step<0x111, 0xF>(v);   // row_shr:1
    v = dpp_add_step<0x112, 0xF>(v);   // row_shr:2
    v = dpp_add_step<0x114, 0xF>(v);   // row_shr:4
    v = dpp_add_step<0x118, 0xF>(v);   // row_shr:8  -> lanes 15/31/47/63
    v = dpp_add_step<0x142, 0xA>(v);   // row_bcast:15 into rows 1,3
    v = dpp_add_step<0x143, 0xC>(v);   // row_bcast:31 into rows 2,3
    return v;
}

// 1 - sigmoid(x) = 1/(1 + e^x); inf-safe without clamps (rcp(inf)=0).
__device__ __forceinline__ float one_minus_sig(float x) {
    float e = __builtin_amdgcn_exp2f(x * 1.4426950408889634f);
    return __builtin_amdgcn_rcpf(1.0f + e);
}

// tanh(x) = 1 - 2/(1 + e^{2x}); saturates correctly at +/-inf, no clamps.
__device__ __forceinline__ float tanh_fast(float x) {
    float e = __builtin_amdgcn_exp2f(x * 2.8853900817779268f);
    return fmaf(-2.0f, __builtin_amdgcn_rcpf(1.0f + e), 1.0f);
}

// LDS-only barrier: orders ds_write/ds_read across waves WITHOUT draining
// the outstanding global stores (__syncthreads would emit s_waitcnt vmcnt(0)
// before s_barrier, putting HBM store latency on the serial scan path).
__device__ __forceinline__ void barrier_lds_only() {
    asm volatile("s_waitcnt lgkmcnt(0)\n\ts_barrier" ::: "memory");
}

// ---------------------------------------------------------------------------
// Fused kernel: sequential scan with the input projection (X = x_t . Wi + bi)
// computed in-loop. The X loads have no recurrence dependence, so each row is
// register-prefetched TWO steps ahead (issue at step t, consume at t+2 —
// ~2700 cycles of slack vs ~900-cycle HBM latency). One block (256 threads,
// 4 waves) per batch element; h,c in registers (6 floats/thread). Per step:
// 36 FMAs, 6 DPP wave reductions (parallel chains), one ds_write/wave + ONE
// lgkm-only barrier (double-buffered red[]), 4 gate evals, 12 tanh, and
// fire-and-forget coalesced global stores never drained inside the loop.
// ---------------------------------------------------------------------------
__global__ __launch_bounds__(256) void scan_fused_kernel(
    const float* __restrict__ inputs,   // (T, B, 1536)
    const float* __restrict__ h0,
    const float* __restrict__ c0,
    const float* __restrict__ Wr, const float* __restrict__ br,
    const float* __restrict__ Wc, const float* __restrict__ bc,
    const float* __restrict__ Wi, const float* __restrict__ bi,
    float* __restrict__ outs,       // (T, B, 1536)
    float* __restrict__ hT,         // (B, 1536)
    float* __restrict__ cT)         // (B, 1536)
{
    const int b    = blockIdx.x;
    const int tid  = threadIdx.x;
    const int wid  = tid >> 6;
    const int lane = tid & 63;

    __shared__ float4 red4[2][4];   // double-buffered: 4 waves x (Hc,Hh,Cc,Ch)
    __shared__ float2 red2[2][4];   // double-buffered: 4 waves x (Xc,Xh)

    const float4 wr0_4 = ((const float4*)Wr)[tid];
    const float4 wr1_4 = ((const float4*)(Wr + FEAT))[tid];
    const float2 wr0_2 = ((const float2*)(Wr + 1024))[tid];
    const float2 wr1_2 = ((const float2*)(Wr + FEAT + 1024))[tid];
    const float4 wc0_4 = ((const float4*)Wc)[tid];
    const float4 wc1_4 = ((const float4*)(Wc + FEAT))[tid];
    const float2 wc0_2 = ((const float2*)(Wc + 1024))[tid];
    const float2 wc1_2 = ((const float2*)(Wc + FEAT + 1024))[tid];
    const float4 wi0_4 = ((const float4*)Wi)[tid];
    const float4 wi1_4 = ((const float4*)(Wi + FEAT))[tid];
    const float2 wi0_2 = ((const float2*)(Wi + 1024))[tid];
    const float2 wi1_2 = ((const float2*)(Wi + FEAT + 1024))[tid];
    const float br0 = br[0], br1 = br[1];
    const float bc0 = bc[0], bc1 = bc[1];
    const float bi0 = bi[0], bi1 = bi[1];

    const float* h0b = h0 + (size_t)b * FEAT;
    const float* c0b = c0 + (size_t)b * FEAT;
    float4 h4 = ((const float4*)h0b)[tid];
    float2 h2 = ((const float2*)(h0b + 1024))[tid];
    float4 c4 = ((const float4*)c0b)[tid];
    float2 c2 = ((const float2*)(c0b + 1024))[tid];

    const float*  xbase   = inputs + (size_t)b * FEAT;
    const size_t  XSTRIDE = (size_t)BATCH * FEAT;

    // Prologue: prefetch rows t=0 (xa) and t=1 (xb).
    float4 xa4 = ((const float4*)xbase)[tid];
    float2 xa2 = ((const float2*)(xbase + 1024))[tid];
    float4 xb4 = ((const float4*)(xbase + XSTRIDE))[tid];
    float2 xb2 = ((const float2*)(xbase + XSTRIDE + 1024))[tid];

    float* op = outs + (size_t)b * FEAT;
    const size_t OSTRIDE = (size_t)BATCH * FEAT;

    auto step = [&](float4* buf4, float2* buf2, int t, float4& x4, float2& x2) {
        float pHc = h4.x * wr0_4.x + h4.y * wr0_4.y + h4.z * wr0_4.z + h4.w * wr0_4.w
                  + h2.x * wr0_2.x + h2.y * wr0_2.y;
        float pHh = h4.x * wr1_4.x + h4.y * wr1_4.y + h4.z * wr1_4.z + h4.w * wr1_4.w
                  + h2.x * wr1_2.x + h2.y * wr1_2.y;
        float pCc = c4.x * wc0_4.x + c4.y * wc0_4.y + c4.z * wc0_4.z + c4.w * wc0_4.w
                  + c2.x * wc0_2.x + c2.y * wc0_2.y;
        float pCh = c4.x * wc1_4.x + c4.y * wc1_4.y + c4.z * wc1_4.z + c4.w * wc1_4.w
                  + c2.x * wc1_2.x + c2.y * wc1_2.y;
        // X projection: identical per-thread partial order to the old xdot
        // kernel (numerics unchanged).
        float pXc = x4.x * wi0_4.x + x4.y * wi0_4.y + x4.z * wi0_4.z + x4.w * wi0_4.w
                  + x2.x * wi0_2.x + x2.y * wi0_2.y;
        float pXh = x4.x * wi1_4.x + x4.y * wi1_4.y + x4.z * wi1_4.z + x4.w * wi1_4.w
                  + x2.x * wi1_2.x + x2.y * wi1_2.y;

        // Prefetch row t+2 into the just-consumed registers (clamped at the
        // tail to avoid OOB; redundant reload of row 255 is harmless).
        {
            const int tn = (t + 2 < T_STEPS) ? (t + 2) : (T_STEPS - 1);
            const float* xp = xbase + (size_t)tn * XSTRIDE;
            x4 = ((const float4*)xp)[tid];
            x2 = ((const float2*)(xp + 1024))[tid];
        }

        pHc = wave_reduce63(pHc);
        pHh = wave_reduce63(pHh);
        pCc = wave_reduce63(pCc);
        pCh = wave_reduce63(pCh);
        pXc = wave_reduce63(pXc);
        pXh = wave_reduce63(pXh);

        if (lane == 63) {
            buf4[wid] = make_float4(pHc, pHh, pCc, pCh);
            buf2[wid] = make_float2(pXc, pXh);
        }
        barrier_lds_only();
        const float4 r0 = buf4[0];
        const float4 r1 = buf4[1];
        const float4 r2 = buf4[2];
        const float4 r3 = buf4[3];
        const float2 s0 = buf2[0];
        const float2 s1 = buf2[1];
        const float2 s2 = buf2[2];
        const float2 s3 = buf2[3];
        const float Hc = r0.x + r1.x + r2.x + r3.x + br0;
        const float Hh = r0.y + r1.y + r2.y + r3.y + br1;
        const float Cc = r0.z + r1.z + r2.z + r3.z + bc0;
        const float Ch = r0.w + r1.w + r2.w + r3.w + bc1;
        const float Xc = s0.x + s1.x + s2.x + s3.x + bi0;
        const float Xh = s0.y + s1.y + s2.y + s3.y + bi1;

        // gh = (1-sig(Ch))*Xh + (1-sig(Hh))*h ; gc = (1-sig(Hc))*Xc + (1-sig(Cc))*c
        const float Ah = one_minus_sig(Ch) * Xh;
        const float Sh = one_minus_sig(Hh);
        const float Ac = one_minus_sig(Hc) * Xc;
        const float Sc = one_minus_sig(Cc);

        h4.x = tanh_fast(fmaf(Sh, h4.x, Ah));
        h4.y = tanh_fast(fmaf(Sh, h4.y, Ah));
        h4.z = tanh_fast(fmaf(Sh, h4.z, Ah));
        h4.w = tanh_fast(fmaf(Sh, h4.w, Ah));
        h2.x = tanh_fast(fmaf(Sh, h2.x, Ah));
        h2.y = tanh_fast(fmaf(Sh, h2.y, Ah));

        c4.x = tanh_fast(fmaf(Sc, c4.x, Ac));
        c4.y = tanh_fast(fmaf(Sc, c4.y, Ac));
        c4.z = tanh_fast(fmaf(Sc, c4.z, Ac));
        c4.w = tanh_fast(fmaf(Sc, c4.w, Ac));
        c2.x = tanh_fast(fmaf(Sc, c2.x, Ac));
        c2.y = tanh_fast(fmaf(Sc, c2.y, Ac));

        // outs[t, b, :] = ht (fire-and-forget; never drained inside the loop)
        ((float4*)op)[tid]          = h4;
        ((float2*)(op + 1024))[tid] = h2;
        op += OSTRIDE;
        // Double-buffer safety with ONE barrier/step: a wave's re-write of
        // buf (step t+2) happens after barrier t+1, which every wave reaches
        // only after its step-t read of this buffer.
    };

#pragma unroll 1
    for (int t = 0; t < T_STEPS; t += 2) {
        step(red4[0], red2[0], t,     xa4, xa2);
        step(red4[1], red2[1], t + 1, xb4, xb2);
    }

    float* hp = hT + (size_t)b * FEAT;
    ((float4*)hp)[tid]          = h4;
    ((float2*)(hp + 1024))[tid] = h2;
    float* cp = cT + (size_t)b * FEAT;
    ((float4*)cp)[tid]          = c4;
    ((float2*)(cp + 1024))[tid] = c2;
}

extern "C" void kernel_launch(void* const* d_in, const int* in_sizes, int n_in,
                              void* d_out, int out_size, void* d_ws, size_t ws_size,
                              hipStream_t stream) {
    const float* inputs = (const float*)d_in[0];
    const float* h0     = (const float*)d_in[1];
    const float* c0     = (const float*)d_in[2];
    const float* Wr     = (const float*)d_in[3];
    const float* br     = (const float*)d_in[4];
    const float* Wc     = (const float*)d_in[5];
    const float* bc     = (const float*)d_in[6];
    const float* Wi     = (const float*)d_in[7];
    const float* bi     = (const float*)d_in[8];

    float* out  = (float*)d_out;
    float* outs = out;                                        // (T,B,1536)
    float* hT   = out + (size_t)NPAIRS * FEAT;                // (B,1536)
    float* cT   = hT + (size_t)BATCH * FEAT;                  // (B,1536)

    scan_fused_kernel<<<BATCH, 256, 0, stream>>>(inputs, h0, c0, Wr, br,
                                                 Wc, bc, Wi, bi,
                                                 outs, hT, cT);
}

// Round 2
// 426.419 us; speedup vs baseline: 1.0548x; 1.0370x over previous
//
#include <hip/hip_runtime.h>

#define T_STEPS 256
#define BATCH   128
#define FEAT    1536            // DH * L = 512 * 3
#define NPAIRS  (T_STEPS * BATCH)

// ---------------------------------------------------------------------------
// DPP full-wave (64-lane) sum. Result valid in lane 63. All VALU-pipe.
// ---------------------------------------------------------------------------
template <int CTRL, int RMASK>
__device__ __forceinline__ float dpp_add_step(float v) {
    int m = __builtin_amdgcn_update_dpp(0, __float_as_int(v), CTRL, RMASK, 0xF, true);
    return v + __int_as_float(m);
}

__device__ __forceinline__ float wave_reduce63(float v) {
    v = dpp_add_step<0x111, 0xF>(v);   // row_shr:1
    v = dpp_add_step<0x112, 0xF>(v);   // row_shr:2
    v = dpp_add_step<0x114, 0xF>(v);   // row_shr:4
    v = dpp_add_step<0x118, 0xF>(v);   // row_shr:8  -> lanes 15/31/47/63
    v = dpp_add_step<0x142, 0xA>(v);   // row_bcast:15 into rows 1,3
    v = dpp_add_step<0x143, 0xC>(v);   // row_bcast:31 into rows 2,3
    return v;
}

// 1 - sigmoid(x) = 1/(1 + e^x); inf-safe without clamps (rcp(inf)=0).
__device__ __forceinline__ float one_minus_sig(float x) {
    float e = __builtin_amdgcn_exp2f(x * 1.4426950408889634f);
    return __builtin_amdgcn_rcpf(1.0f + e);
}

// tanh(x) = 1 - 2/(1 + e^{2x}); saturates correctly at +/-inf, no clamps.
__device__ __forceinline__ float tanh_fast(float x) {
    float e = __builtin_amdgcn_exp2f(x * 2.8853900817779268f);
    return fmaf(-2.0f, __builtin_amdgcn_rcpf(1.0f + e), 1.0f);
}

// LDS-only barrier: orders ds_write/ds_read across waves WITHOUT draining
// the outstanding global stores (__syncthreads would emit s_waitcnt vmcnt(0)
// before s_barrier, putting HBM store latency on the serial scan path).
__device__ __forceinline__ void barrier_lds_only() {
    asm volatile("s_waitcnt lgkmcnt(0)\n\ts_barrier" ::: "memory");
}

// ---------------------------------------------------------------------------
// Fused scan with software-pipelined input projection.
// Pipeline schedule (per block = one batch element, 4 waves):
//   - x rows held in 4 rotating REGISTER buffers (static indices via x4
//     manual unroll), refilled at distance 4: issue row t+5 at step t,
//     consume (FMA+reduce) at step t+4 -> ~4 steps of slack vs ~900cy HBM.
//   - X reduction runs ONE STEP EARLY: step t computes/reduces X(t+1) in the
//     post-barrier region and drops partials into a 4-deep LDS ring XR.
//     Step t's gates read X(t) from XR[(t-1)&3] (exchanged last step), so
//     neither the x-load wait nor the X DPP-chain latency is on the
//     recurrence critical path -- only ~12 FMA + 12 DPP of issue remains.
//   - Ring safety: XR[t&3] written at step t (pre barrier_{t+1}), read at
//     step t+1 (post barrier_{t+1}), rewritten at step t+4 -- 2 barriers of
//     margin. H/C exchange keeps the proven double-buffer + ONE lgkm-only
//     barrier per step. Output stores stay fire-and-forget.
// ---------------------------------------------------------------------------
__global__ __launch_bounds__(256) void scan_fused_kernel(
    const float* __restrict__ inputs,   // (T, B, 1536)
    const float* __restrict__ h0,
    const float* __restrict__ c0,
    const float* __restrict__ Wr, const float* __restrict__ br,
    const float* __restrict__ Wc, const float* __restrict__ bc,
    const float* __restrict__ Wi, const float* __restrict__ bi,
    float* __restrict__ outs,       // (T, B, 1536)
    float* __restrict__ hT,         // (B, 1536)
    float* __restrict__ cT)         // (B, 1536)
{
    const int b    = blockIdx.x;
    const int tid  = threadIdx.x;
    const int wid  = tid >> 6;
    const int lane = tid & 63;

    __shared__ float4 red4[2][4];   // double-buffered: 4 waves x (Hc,Hh,Cc,Ch)
    __shared__ float2 XR[4][4];     // 4-deep ring: 4 waves x (Xc,Xh) partials

    const float4 wr0_4 = ((const float4*)Wr)[tid];
    const float4 wr1_4 = ((const float4*)(Wr + FEAT))[tid];
    const float2 wr0_2 = ((const float2*)(Wr + 1024))[tid];
    const float2 wr1_2 = ((const float2*)(Wr + FEAT + 1024))[tid];
    const float4 wc0_4 = ((const float4*)Wc)[tid];
    const float4 wc1_4 = ((const float4*)(Wc + FEAT))[tid];
    const float2 wc0_2 = ((const float2*)(Wc + 1024))[tid];
    const float2 wc1_2 = ((const float2*)(Wc + FEAT + 1024))[tid];
    const float4 wi0_4 = ((const float4*)Wi)[tid];
    const float4 wi1_4 = ((const float4*)(Wi + FEAT))[tid];
    const float2 wi0_2 = ((const float2*)(Wi + 1024))[tid];
    const float2 wi1_2 = ((const float2*)(Wi + FEAT + 1024))[tid];
    const float br0 = br[0], br1 = br[1];
    const float bc0 = bc[0], bc1 = bc[1];
    const float bi0 = bi[0], bi1 = bi[1];

    const float* h0b = h0 + (size_t)b * FEAT;
    const float* c0b = c0 + (size_t)b * FEAT;
    float4 h4 = ((const float4*)h0b)[tid];
    float2 h2 = ((const float2*)(h0b + 1024))[tid];
    float4 c4 = ((const float4*)c0b)[tid];
    float2 c2 = ((const float2*)(c0b + 1024))[tid];

    const float*  xbase   = inputs + (size_t)b * FEAT;
    const size_t  XSTRIDE = (size_t)BATCH * FEAT;

    // ---- Prologue: compute X(0) fully (same partial order as before) ----
    {
        const float4 x4 = ((const float4*)xbase)[tid];
        const float2 x2 = ((const float2*)(xbase + 1024))[tid];
        float pXc = x4.x * wi0_4.x + x4.y * wi0_4.y + x4.z * wi0_4.z + x4.w * wi0_4.w
                  + x2.x * wi0_2.x + x2.y * wi0_2.y;
        float pXh = x4.x * wi1_4.x + x4.y * wi1_4.y + x4.z * wi1_4.z + x4.w * wi1_4.w
                  + x2.x * wi1_2.x + x2.y * wi1_2.y;
        pXc = wave_reduce63(pXc);
        pXh = wave_reduce63(pXh);
        if (lane == 63) XR[3][wid] = make_float2(pXc, pXh);  // slot (0-1)&3
    }

    // ---- Prefetch rows 1..4 into rotating slots 1,2,3,0 (slot = row&3) ----
    float4 R1_4 = ((const float4*)(xbase + 1 * XSTRIDE))[tid];
    float2 R1_2 = ((const float2*)(xbase + 1 * XSTRIDE + 1024))[tid];
    float4 R2_4 = ((const float4*)(xbase + 2 * XSTRIDE))[tid];
    float2 R2_2 = ((const float2*)(xbase + 2 * XSTRIDE + 1024))[tid];
    float4 R3_4 = ((const float4*)(xbase + 3 * XSTRIDE))[tid];
    float2 R3_2 = ((const float2*)(xbase + 3 * XSTRIDE + 1024))[tid];
    float4 R0_4 = ((const float4*)(xbase + 4 * XSTRIDE))[tid];
    float2 R0_2 = ((const float2*)(xbase + 4 * XSTRIDE + 1024))[tid];

    float* op = outs + (size_t)b * FEAT;
    const size_t OSTRIDE = (size_t)BATCH * FEAT;

    __syncthreads();   // XR[3] visible (one-time; vmcnt drain harmless here)

    // step t: consume x-row registers holding row t+1, refill with row t+5,
    // exchange X(t+1) partials into XR[sw=t&3]; gates read X(t) from XR[sr].
    auto step = [&](float4* buf, float4& rx4, float2& rx2, int t, int sw, int sr) {
        float pHc = h4.x * wr0_4.x + h4.y * wr0_4.y + h4.z * wr0_4.z + h4.w * wr0_4.w
                  + h2.x * wr0_2.x + h2.y * wr0_2.y;
        float pHh = h4.x * wr1_4.x + h4.y * wr1_4.y + h4.z * wr1_4.z + h4.w * wr1_4.w
                  + h2.x * wr1_2.x + h2.y * wr1_2.y;
        float pCc = c4.x * wc0_4.x + c4.y * wc0_4.y + c4.z * wc0_4.z + c4.w * wc0_4.w
                  + c2.x * wc0_2.x + c2.y * wc0_2.y;
        float pCh = c4.x * wc1_4.x + c4.y * wc1_4.y + c4.z * wc1_4.z + c4.w * wc1_4.w
                  + c2.x * wc1_2.x + c2.y * wc1_2.y;

        pHc = wave_reduce63(pHc);
        pHh = wave_reduce63(pHh);
        pCc = wave_reduce63(pCc);
        pCh = wave_reduce63(pCh);

        if (lane == 63) {
            buf[wid] = make_float4(pHc, pHh, pCc, pCh);
        }
        barrier_lds_only();
        const float4 r0 = buf[0];
        const float4 r1 = buf[1];
        const float4 r2 = buf[2];
        const float4 r3 = buf[3];
        const float2 s0 = XR[sr][0];
        const float2 s1 = XR[sr][1];
        const float2 s2 = XR[sr][2];
        const float2 s3 = XR[sr][3];

        // ---- X pipeline for row t+1 (result needed only at step t+1) ----
        float pXc = rx4.x * wi0_4.x + rx4.y * wi0_4.y + rx4.z * wi0_4.z + rx4.w * wi0_4.w
                  + rx2.x * wi0_2.x + rx2.y * wi0_2.y;
        float pXh = rx4.x * wi1_4.x + rx4.y * wi1_4.y + rx4.z * wi1_4.z + rx4.w * wi1_4.w
                  + rx2.x * wi1_2.x + rx2.y * wi1_2.y;
        {   // refill this slot with row t+5 (clamped; tail reloads row 255,
            // whose result is never consumed)
            const int tn = (t + 5 < T_STEPS) ? (t + 5) : (T_STEPS - 1);
            const float* xp = xbase + (size_t)tn * XSTRIDE;
            rx4 = ((const float4*)xp)[tid];
            rx2 = ((const float2*)(xp + 1024))[tid];
        }
        pXc = wave_reduce63(pXc);
        pXh = wave_reduce63(pXh);
        if (lane == 63) {
            XR[sw][wid] = make_float2(pXc, pXh);   // covered by next barrier
        }

        const float Hc = r0.x + r1.x + r2.x + r3.x + br0;
        const float Hh = r0.y + r1.y + r2.y + r3.y + br1;
        const float Cc = r0.z + r1.z + r2.z + r3.z + bc0;
        const float Ch = r0.w + r1.w + r2.w + r3.w + bc1;
        const float Xc = s0.x + s1.x + s2.x + s3.x + bi0;
        const float Xh = s0.y + s1.y + s2.y + s3.y + bi1;

        // gh = (1-sig(Ch))*Xh + (1-sig(Hh))*h ; gc = (1-sig(Hc))*Xc + (1-sig(Cc))*c
        const float Ah = one_minus_sig(Ch) * Xh;
        const float Sh = one_minus_sig(Hh);
        const float Ac = one_minus_sig(Hc) * Xc;
        const float Sc = one_minus_sig(Cc);

        h4.x = tanh_fast(fmaf(Sh, h4.x, Ah));
        h4.y = tanh_fast(fmaf(Sh, h4.y, Ah));
        h4.z = tanh_fast(fmaf(Sh, h4.z, Ah));
        h4.w = tanh_fast(fmaf(Sh, h4.w, Ah));
        h2.x = tanh_fast(fmaf(Sh, h2.x, Ah));
        h2.y = tanh_fast(fmaf(Sh, h2.y, Ah));

        c4.x = tanh_fast(fmaf(Sc, c4.x, Ac));
        c4.y = tanh_fast(fmaf(Sc, c4.y, Ac));
        c4.z = tanh_fast(fmaf(Sc, c4.z, Ac));
        c4.w = tanh_fast(fmaf(Sc, c4.w, Ac));
        c2.x = tanh_fast(fmaf(Sc, c2.x, Ac));
        c2.y = tanh_fast(fmaf(Sc, c2.y, Ac));

        // outs[t, b, :] = ht (fire-and-forget; never drained inside the loop)
        ((float4*)op)[tid]          = h4;
        ((float2*)(op + 1024))[tid] = h2;
        op += OSTRIDE;
    };

#pragma unroll 1
    for (int t = 0; t < T_STEPS; t += 4) {
        step(red4[0], R1_4, R1_2, t,     0, 3);
        step(red4[1], R2_4, R2_2, t + 1, 1, 0);
        step(red4[0], R3_4, R3_2, t + 2, 2, 1);
        step(red4[1], R0_4, R0_2, t + 3, 3, 2);
    }

    float* hp = hT + (size_t)b * FEAT;
    ((float4*)hp)[tid]          = h4;
    ((float2*)(hp + 1024))[tid] = h2;
    float* cp = cT + (size_t)b * FEAT;
    ((float4*)cp)[tid]          = c4;
    ((float2*)(cp + 1024))[tid] = c2;
}

extern "C" void kernel_launch(void* const* d_in, const int* in_sizes, int n_in,
                              void* d_out, int out_size, void* d_ws, size_t ws_size,
                              hipStream_t stream) {
    const float* inputs = (const float*)d_in[0];
    const float* h0     = (const float*)d_in[1];
    const float* c0     = (const float*)d_in[2];
    const float* Wr     = (const float*)d_in[3];
    const float* br     = (const float*)d_in[4];
    const float* Wc     = (const float*)d_in[5];
    const float* bc     = (const float*)d_in[6];
    const float* Wi     = (const float*)d_in[7];
    const float* bi     = (const float*)d_in[8];

    float* out  = (float*)d_out;
    float* outs = out;                                        // (T,B,1536)
    float* hT   = out + (size_t)NPAIRS * FEAT;                // (B,1536)
    float* cT   = hT + (size_t)BATCH * FEAT;                  // (B,1536)

    scan_fused_kernel<<<BATCH, 256, 0, stream>>>(inputs, h0, c0, Wr, br,
                                                 Wc, bc, Wi, bi,
                                                 outs, hT, cT);
}